// Round 10
// baseline (116.458 us; speedup 1.0000x reference)
//
#include <hip/hip_runtime.h>

#define BATCH 32768
#define LEN   1024
#define TT    16      // timesteps per tile
#define NTK   64      // total tiles
#define WV    8       // waves per block (one tile each per round)
#define PB    64      // batch paths per block (1 per lane)
#define TS    36      // ttile row stride in floats (2*TT + 4, 16B-aligned)

typedef float f32x4 __attribute__((ext_vector_type(4)));

// Affine-scan time-parallel SDE, 2-blocks/CU edition.
//   x_{t+1} = q*x_t + (Ax*zx + Bx*zy),  q = 1-h
//   y_{t+1} = y_t + h*x_{t+1} + sh*zy
// Tile k (16 steps) from zero state; rank-1 fix with entry state (u,v):
//   slot j:  x += u*q^(j+1);  y += v + u*q*(1-q^(j+1))
// Round r: waves 0..7 compute tiles 8r+w-off; wave-0 scan stitches entry
// states; writeout = one 1KB-contiguous nt float4 store per out row.

#define BAR() do { asm volatile("s_waitcnt lgkmcnt(0)" ::: "memory"); \
                   __builtin_amdgcn_s_barrier(); } while (0)

#define STEP(ZI) do { \
    x = fmaf(x, q, fmaf(Ax, ZI.x, Bx * ZI.y)); \
    y = y + fmaf(x, h, sh * ZI.y); \
} while (0)

// One round. R compile-time; CUR/NXT distinct register arrays (rule #20).
#define ROUND(R, CUR, NXT, PRE_, FIRST_) do { \
    const int k_ = 8 * (R) + w - off; \
    if (PRE_) {  /* issue next round's z slab first: flies all round */ \
        const int kn_ = 8 * ((R) + 1) + w - off;   /* >= 1 when valid */ \
        if ((unsigned)kn_ < (unsigned)NTK) { \
            const int rowb_ = 16 * kn_ - 1; \
            _Pragma("unroll") \
            for (int j = 0; j < TT; ++j) \
                NXT[j] = zb2[(size_t)(rowb_ + j) * BATCH]; \
        } \
    } \
    if ((unsigned)k_ < (unsigned)NTK) { \
        float x, y; \
        if (FIRST_ && k_ == 0) { x = xiv; y = yiv; } \
        else                   { x = 0.f; y = 0.f; } \
        float* tb_ = ttile + (w * PB + lane) * TS; \
        _Pragma("unroll") \
        for (int j = 0; j < TT; j += 2) { \
            float2 p0_; \
            if (FIRST_ && k_ == 0 && j == 0) { \
                p0_ = make_float2(x, y);            /* slot 0 = IC */ \
            } else { \
                const float2 z0_ = CUR[j]; STEP(z0_); \
                p0_ = make_float2(x, y); \
            } \
            const float2 z1_ = CUR[j + 1]; STEP(z1_); \
            *(float4*)&tb_[4 * ((j >> 1) ^ csw)] = make_float4(p0_.x, p0_.y, x, y); \
        } \
        arr[w][lane] = make_float2(x, y);           /* tile end state */ \
    } \
    BAR();  /* A: summaries + trajectories visible */ \
    if (w == 0) { \
        _Pragma("unroll") \
        for (int wp = 0; wp < WV; ++wp) { \
            const int kp_ = 8 * (R) + wp - off; \
            if ((unsigned)kp_ < (unsigned)NTK) { \
                const float2 s_ = arr[wp][lane]; \
                arr[wp][lane] = make_float2(U, V);  /* entry state */ \
                const float nU_ = fmaf(ALPHA, U, s_.x); \
                V = s_.y + V + GAL * U;  U = nU_; \
            } \
        } \
    } \
    BAR();  /* B: entry-state corrections visible */ \
    { \
        const int kw_ = 8 * (R) + wl - off;         /* per-lane tile */ \
        if ((unsigned)kw_ < (unsigned)NTK) { \
            const int colf_ = (8 * (R) - off) * 32 + 32 * wl + 4 * sl; \
            _Pragma("unroll") \
            for (int i = 0; i < 8; ++i) { \
                const int row_ = w * 8 + i; \
                const float4 t_ = *(const float4*)&ttile[ \
                    (wl * PB + row_) * TS + 4 * (sl ^ (row_ & 7))]; \
                const float2 uv_ = arr[wl][row_]; \
                f32x4 o_; \
                o_.x = fmaf(uv_.x, a0, t_.x); \
                o_.y = t_.y + uv_.y + uv_.x * g0; \
                o_.z = fmaf(uv_.x, a1, t_.z); \
                o_.w = t_.w + uv_.y + uv_.x * g1; \
                __builtin_nontemporal_store(o_, \
                    (f32x4*)&out[(size_t)(bb + row_) * 2048 + colf_]); \
            } \
        } \
    } \
    BAR();  /* C: ttile/arr free for next round */ \
} while (0)

__global__ __launch_bounds__(512, 4)
void sde_kernel(const float* __restrict__ x0,
                const float* __restrict__ y0,
                const float* __restrict__ ts,
                const float* __restrict__ z,    // (L-1, BATCH, 2) fp32
                float* __restrict__ out)        // (BATCH, L, 2) fp32
{
    const int tid  = threadIdx.x;
    const int lane = tid & 63;
    const int w    = tid >> 6;
    const int bb   = blockIdx.x * PB;

    __shared__ __align__(16) float  ttile[WV * PB * TS];  // 73,728 B
    __shared__ __align__(16) float2 arr[WV][66];          //  4,224 B

    const float h  = (ts[LEN - 1] - ts[0]) * (1.0f / 1023.0f);
    const float q  = 1.0f - h;
    const float sh = sqrtf(h);
    const float Ax = 0.075f * sh;          // SIGMA*RHO^2*sqrt(h)
    const float Bx = 0.225f * sh;          // SIGMA*(1-RHO^2)*sqrt(h)
    const float q2 = q * q, q4 = q2 * q2, q8 = q4 * q4;
    const float ALPHA = q8 * q8;           // q^16
    const float GAL   = q * (1.0f - ALPHA);

    const int off = blockIdx.x & 7;        // tile-phase stagger

    const float xiv = x0[bb + lane];
    const float yiv = y0[bb + lane];

    const int   csw = lane & 7;            // LDS slot-pair swizzle key (=path&7)
    const int   wl  = lane >> 3;           // writeout: tile group
    const int   sl  = lane & 7;            // writeout: slot-pair
    const float a0 = exp2f((float)(2 * sl + 1) * log2f(q));  // q^(j+1), j=2*sl
    const float a1 = a0 * q;                                  // q^(j+2)
    const float g0 = q * (1.0f - a0);
    const float g1 = q * (1.0f - a1);

    const float2* zb2 = (const float2*)z + bb + lane;  // + row*BATCH

    float U = 0.f, V = 0.f;                // wave-0 scan carry

    float2 zvA[TT], zvB[TT];

    // prologue: round-0 slab (tile w-off; clamp for k==0's unused slot 0)
    {
        const int k0 = w - off;
        if ((unsigned)k0 < (unsigned)NTK) {
            const int rowb = 16 * k0 - 1;
#pragma unroll
            for (int j = 0; j < TT; ++j) {
                int row = rowb + j;
                row = row < 0 ? 0 : row;
                zvA[j] = zb2[(size_t)row * BATCH];
            }
        }
    }

    ROUND(0, zvA, zvB, 1, 1);
    ROUND(1, zvB, zvA, 1, 0);
    ROUND(2, zvA, zvB, 1, 0);
    ROUND(3, zvB, zvA, 1, 0);
    ROUND(4, zvA, zvB, 1, 0);
    ROUND(5, zvB, zvA, 1, 0);
    ROUND(6, zvA, zvB, 1, 0);
    ROUND(7, zvB, zvA, 1, 0);
    ROUND(8, zvA, zvB, 0, 0);   // ragged tail (off>0 blocks); off=0 idles
}

extern "C" void kernel_launch(void* const* d_in, const int* in_sizes, int n_in,
                              void* d_out, int out_size, void* d_ws, size_t ws_size,
                              hipStream_t stream) {
    const float* x0 = (const float*)d_in[0];
    const float* y0 = (const float*)d_in[1];
    const float* ts = (const float*)d_in[2];
    const float* z  = (const float*)d_in[3];
    float* out = (float*)d_out;
    (void)d_ws; (void)ws_size; (void)in_sizes; (void)n_in; (void)out_size;

    sde_kernel<<<BATCH / PB, 512, 0, stream>>>(x0, y0, ts, z, out);
}

// Round 11
// 90.531 us; speedup vs baseline: 1.2864x; 1.2864x over previous
//
#include <hip/hip_runtime.h>

#define BATCH 32768
#define LEN   1024
#define TT    16      // timesteps per tile
#define NTK   64      // total tiles
#define WV    8       // waves per block (one tile each per round)
#define PB    128     // batch paths per block (2 per lane)

typedef float f32x4 __attribute__((ext_vector_type(4)));

// Affine-scan time-parallel SDE. Round r: waves 0..7 compute tiles 8r+w-off
// from zero state; wave-0 affine scan stitches entry states (u,v); writeout
// applies the rank-1 correction and emits one 1KB-contiguous nt store per row.
// Config proven optimal over r0-r10: 1 block/CU, 1KB bursts both streams,
// nt stores (L3 reserved for z), register z double-buffer across raw barriers.

// LDS-only barrier: drain DS ops, keep vmem (prefetch loads, nt stores) flying.
#define BAR() do { asm volatile("s_waitcnt lgkmcnt(0)" ::: "memory"); \
                   __builtin_amdgcn_s_barrier(); } while (0)

#define STEP(ZI) do { \
    xa = fmaf(xa, q, fmaf(Ax, ZI.x, Bx * ZI.y)); \
    ya = ya + fmaf(xa, h, sh * ZI.y); \
    xb = fmaf(xb, q, fmaf(Ax, ZI.z, Bx * ZI.w)); \
    yb = yb + fmaf(xb, h, sh * ZI.w); \
} while (0)

// One round. R compile-time; CUR/NXT are distinct register arrays (rule #20).
#define ROUND(R, CUR, NXT, PRE_, FIRST_) do { \
    const int k_ = 8 * (R) + w - off; \
    if (PRE_) {  /* issue next round's z slab first: flies all round */ \
        const int kn_ = 8 * ((R) + 1) + w - off;   /* >=1 when valid */ \
        if ((unsigned)kn_ < (unsigned)NTK) { \
            const int rowb_ = 16 * kn_ - 1; \
            _Pragma("unroll") \
            for (int j = 0; j < TT; ++j) \
                NXT[j] = zb4[(size_t)(rowb_ + j) << 14]; \
        } \
    } \
    if ((unsigned)k_ < (unsigned)NTK) { \
        float xa, ya, xb, yb; \
        if (FIRST_ && k_ == 0) { xa = xi.x; ya = yi.x; xb = xi.y; yb = yi.y; } \
        else                   { xa = 0.f;  ya = 0.f;  xb = 0.f;  yb = 0.f;  } \
        float* tb0_ = ttile + ((size_t)w * PB + 2 * lane) * 36; \
        _Pragma("unroll") \
        for (int j = 0; j < TT; j += 2) { \
            float2 pa0_, pb0_; \
            if (FIRST_ && k_ == 0 && j == 0) { \
                pa0_ = make_float2(xa, ya); pb0_ = make_float2(xb, yb); \
            } else { \
                const float4 zi_ = CUR[j]; STEP(zi_); \
                pa0_ = make_float2(xa, ya); pb0_ = make_float2(xb, yb); \
            } \
            const float4 zi1_ = CUR[j + 1]; STEP(zi1_); \
            const int o_ = 4 * ((j >> 1) ^ csw); \
            *(float4*)&tb0_[o_]      = make_float4(pa0_.x, pa0_.y, xa, ya); \
            *(float4*)&tb0_[36 + o_] = make_float4(pb0_.x, pb0_.y, xb, yb); \
        } \
        *(float4*)&arr[w][4 * lane] = make_float4(xa, ya, xb, yb); \
    } \
    BAR();  /* A: summaries + trajectories visible */ \
    if (w == 0) { \
        _Pragma("unroll") \
        for (int wp = 0; wp < WV; ++wp) { \
            const int kp_ = 8 * (R) + wp - off; \
            if ((unsigned)kp_ < (unsigned)NTK) { \
                const float4 s_ = *(const float4*)&arr[wp][4 * lane]; \
                *(float4*)&arr[wp][4 * lane] = make_float4(U0, V0, U1, V1); \
                const float nU0_ = fmaf(ALPHA, U0, s_.x); \
                V0 = s_.y + V0 + GAL * U0;  U0 = nU0_; \
                const float nU1_ = fmaf(ALPHA, U1, s_.z); \
                V1 = s_.w + V1 + GAL * U1;  U1 = nU1_; \
            } \
        } \
    } \
    BAR();  /* B: entry-state corrections visible */ \
    { \
        const int kw_ = 8 * (R) + wt - off; \
        if ((unsigned)kw_ < (unsigned)NTK) { \
            const int colf_ = (8 * (R) - off) * 32 + 4 * lane; \
            _Pragma("unroll") \
            for (int i = 0; i < 16; ++i) { \
                const int p_ = w * 16 + i; \
                const float4 t_ = *(const float4*)&ttile[ \
                    ((size_t)wt * PB + p_) * 36 + 4 * (csw ^ ((p_ >> 1) & 7))]; \
                const float2 uv_ = *(const float2*)&arr[wt][2 * p_]; \
                f32x4 o_; \
                o_.x = fmaf(uv_.x, a0, t_.x); \
                o_.y = t_.y + uv_.y + uv_.x * g0; \
                o_.z = fmaf(uv_.x, a1, t_.z); \
                o_.w = t_.w + uv_.y + uv_.x * g1; \
                __builtin_nontemporal_store(o_, \
                    (f32x4*)&out[(size_t)(bb + p_) * 2048 + colf_]); \
            } \
        } \
    } \
    BAR();  /* C: ttile/arr free for next round's writes */ \
} while (0)

__global__ __launch_bounds__(512, 2)
void sde_kernel(const float* __restrict__ x0,
                const float* __restrict__ y0,
                const float* __restrict__ ts,
                const float* __restrict__ z,    // (L-1, BATCH, 2) fp32
                float* __restrict__ out)        // (BATCH, L, 2) fp32
{
    const int tid  = threadIdx.x;
    const int lane = tid & 63;
    const int w    = tid >> 6;
    const int bb   = blockIdx.x * PB;

    // ttile: [wave][path][8 slot-pairs as float4, XOR-swizzled] = 147456 B
    __shared__ __align__(16) float ttile[WV * PB * 36];
    __shared__ __align__(16) float arr[WV][260];     // 128 paths x (u,v) + pad

    const float h  = (ts[LEN - 1] - ts[0]) * (1.0f / 1023.0f);
    const float q  = 1.0f - h;
    const float sh = sqrtf(h);
    const float Ax = 0.075f * sh;          // SIGMA*RHO^2*sqrt(h)
    const float Bx = 0.225f * sh;          // SIGMA*(1-RHO^2)*sqrt(h)
    const float q2 = q * q, q4 = q2 * q2, q8 = q4 * q4;
    const float ALPHA = q8 * q8;           // q^16
    const float GAL   = q * (1.0f - ALPHA);

    const int off = blockIdx.x & 7;        // tile-phase stagger

    const float2 xi = *(const float2*)&x0[bb + 2 * lane];
    const float2 yi = *(const float2*)&y0[bb + 2 * lane];

    const int   csw  = lane & 7;           // LDS slot-pair swizzle key
    const int   jloc = (2 * lane) & 15;
    const float a0 = exp2f((float)(jloc + 1) * log2f(q));  // q^(j+1)
    const float a1 = a0 * q;
    const float g0 = q * (1.0f - a0);
    const float g1 = q * (1.0f - a1);
    const int   wt = lane >> 3;

    const float4* zb4 = (const float4*)z + (bb >> 1) + lane;  // + row*16384

    float U0 = 0.f, V0 = 0.f, U1 = 0.f, V1 = 0.f;

    float4 zvA[TT], zvB[TT];

    // prologue: round-0 slab (tile w-off; row clamp for k==0's unused slot 0)
    {
        const int k0 = w - off;
        if ((unsigned)k0 < (unsigned)NTK) {
            const int rowb = 16 * k0 - 1;
#pragma unroll
            for (int j = 0; j < TT; ++j) {
                int row = rowb + j;
                row = row < 0 ? 0 : row;
                zvA[j] = zb4[(size_t)row << 14];
            }
        }
    }

    ROUND(0, zvA, zvB, 1, 1);
    ROUND(1, zvB, zvA, 1, 0);
    ROUND(2, zvA, zvB, 1, 0);
    ROUND(3, zvB, zvA, 1, 0);
    ROUND(4, zvA, zvB, 1, 0);
    ROUND(5, zvB, zvA, 1, 0);
    ROUND(6, zvA, zvB, 1, 0);
    ROUND(7, zvB, zvA, 1, 0);
    ROUND(8, zvA, zvB, 0, 0);   // ragged tail (off>0 blocks); off=0 idles
}

extern "C" void kernel_launch(void* const* d_in, const int* in_sizes, int n_in,
                              void* d_out, int out_size, void* d_ws, size_t ws_size,
                              hipStream_t stream) {
    const float* x0 = (const float*)d_in[0];
    const float* y0 = (const float*)d_in[1];
    const float* ts = (const float*)d_in[2];
    const float* z  = (const float*)d_in[3];
    float* out = (float*)d_out;
    (void)d_ws; (void)ws_size; (void)in_sizes; (void)n_in; (void)out_size;

    sde_kernel<<<BATCH / PB, 512, 0, stream>>>(x0, y0, ts, z, out);
}